// Round 22
// baseline (72.916 us; speedup 1.0000x reference)
//
#include <hip/hip_runtime.h>
#include <math.h>

#define TDIM 1000
#define BDIM 32
#define VDIM 1000
#define UDIM 100
#define SDIM 201              // 2*U+1
#define EROW 104              // padded pair-row stride (102 used)
#define LN2   0.6931471805599453f
#define PIPE 16               // k_alpha pipeline depth (R20-proven)
#define NROWS (TDIM * BDIM)   // 32000 softmax rows
#define P1_BLOCKS 2048        // phase-1 grid (grid-stride, 8192 waves)
#define P1_STRIDE (P1_BLOCKS * 4)
// Wave max renormalized to 2^110, rescale every 8 steps (PROVEN R11-R20).
#define SCALE_EXP 110

typedef __attribute__((ext_vector_type(2))) float f32x2;
typedef __attribute__((ext_vector_type(4))) float f32x4;
typedef __attribute__((ext_vector_type(4))) int   i32x4;

// med3(x,0,1): 1-instr clamp; NaN input sanitizes to 0.
__device__ __forceinline__ float med3c(float x) {
    return __builtin_amdgcn_fmed3f(x, 0.f, 1.f);
}

// one DPP butterfly level: v += v[xor-partner] (0-fill outside row)
template <int CTRL>
__device__ __forceinline__ float dppadd(float v) {
    int r = __builtin_amdgcn_update_dpp(
        0, __builtin_bit_cast(int, v), CTRL, 0xf, 0xf, true);
    return v + __builtin_bit_cast(float, r);
}

// lane l gets lane l-1's value; lane 0 gets 0.0f (additive identity).
__device__ __forceinline__ float dpp_shr1_zero(float x) {
    int r = __builtin_amdgcn_update_dpp(
        0, __builtin_bit_cast(int, x), 0x138, 0xf, 0xf, true);
    return __builtin_bit_cast(float, r);
}

// one butterfly level of a wave64 max-reduce (p >= 0, so 0-fill is identity)
template <int CTRL>
__device__ __forceinline__ float dppmax(float v) {
    int r = __builtin_amdgcn_update_dpp(
        0, __builtin_bit_cast(int, v), CTRL, 0xf, 0xf, true);
    return fmaxf(v, __builtin_bit_cast(float, r));
}

// ---------------------------------------------------------------------------
// Phase 1 (R22): grid-stride, TWO-ROW software pipeline per wave. Each wave
// owns rows gw, gw+8192, ... and issues the NEXT row's 4 buffer_load_dwordx4
// (inline asm -- unsinkable, R4 lesson) before computing the current row, so
// HBM requests flow through the ~400cy compute+gather+store tail that
// previously idled the memory system (measured 64% of achievable BW).
// Per-row math, lane mapping, and reduce order are TEXTUALLY IDENTICAL to
// R20 -> etab bit-identical. Blank in pair slot 100 (lane-50 pair=(blank,0)).
// ---------------------------------------------------------------------------
__global__ __launch_bounds__(256) void k_lsm_gather(
    const float* __restrict__ lp, const int* __restrict__ targets,
    const int* __restrict__ tlen, float* __restrict__ etab)
{
    const int w = threadIdx.x >> 6, l = threadIdx.x & 63;
    const int gw = blockIdx.x * 4 + w;         // global wave id (0..8191)

    // SRD over the whole lp buffer (128 MB, bytes)
    const unsigned long long lpu = (unsigned long long)lp;
    i32x4 srd;
    srd.x = (int)(lpu & 0xffffffffu);
    srd.y = (int)((lpu >> 32) & 0xffffu);
    srd.z = NROWS * VDIM * 4;                  // 128,000,000 bytes
    srd.w = 0x00020000;

#define P1_ISSUE(R0_, R1_, R2_, R3_, ROW_) {                                     \
    const int _vo = (ROW_) * (VDIM * 4) + l * 16;                                \
    asm volatile("buffer_load_dwordx4 %0, %1, %2, 0 offen offset:0"              \
        : "=v"(R0_) : "v"(_vo), "s"(srd));                                       \
    asm volatile("buffer_load_dwordx4 %0, %1, %2, 0 offen offset:1024"           \
        : "=v"(R1_) : "v"(_vo), "s"(srd));                                       \
    asm volatile("buffer_load_dwordx4 %0, %1, %2, 0 offen offset:2048"           \
        : "=v"(R2_) : "v"(_vo), "s"(srd));                                       \
    asm volatile("buffer_load_dwordx4 %0, %1, %2, 0 offen offset:3072"           \
        : "=v"(R3_) : "v"(_vo), "s"(srd)); }

#define P1_WAIT4(R0_, R1_, R2_, R3_)                                             \
    asm volatile("s_waitcnt vmcnt(4)" : "+v"(R0_), "+v"(R1_), "+v"(R2_), "+v"(R3_));
#define P1_WAIT0(R0_, R1_, R2_, R3_)                                             \
    asm volatile("s_waitcnt vmcnt(0)" : "+v"(R0_), "+v"(R1_), "+v"(R2_), "+v"(R3_));

    // compute + gather + store for one row held in 4 f32x4 registers
#define P1_BODY(V0_, V1_, V2_, V3_, ROW_) {                                      \
    f32x4 v3m = (V3_);                                                           \
    if (l >= 58) { v3m.x = -INFINITY; v3m.y = -INFINITY;                         \
                   v3m.z = -INFINITY; v3m.w = -INFINITY; }                       \
    float s = __expf((V0_).x) + __expf((V0_).y) + __expf((V0_).z) + __expf((V0_).w) \
            + __expf((V1_).x) + __expf((V1_).y) + __expf((V1_).z) + __expf((V1_).w) \
            + __expf((V2_).x) + __expf((V2_).y) + __expf((V2_).z) + __expf((V2_).w) \
            + __expf(v3m.x) + __expf(v3m.y) + __expf(v3m.z) + __expf(v3m.w);     \
    s = dppadd<0xB1>(s);    /* quad_perm xor1  */                                \
    s = dppadd<0x4E>(s);    /* quad_perm xor2  */                                \
    s = dppadd<0x141>(s);   /* row_half_mirror */                                \
    s = dppadd<0x140>(s);   /* row_mirror      */                                \
    s += __shfl_xor(s, 16);                                                      \
    s += __shfl_xor(s, 32);                                                      \
    const float inv_s = __builtin_amdgcn_rcpf(s);                                \
    const int _b = (ROW_) & (BDIM - 1);                                          \
    const int _t = (ROW_) >> 5;                                                  \
    const float* base = lp + (size_t)(ROW_) * VDIM;                              \
    float* erow = etab + (size_t)(_b * TDIM + _t) * EROW;                        \
    const int Sb = 2 * tlen[_b];                                                 \
    if (l < 50) {                                                                \
        const int c0 = targets[_b * UDIM + 2 * l];                               \
        const int c1 = targets[_b * UDIM + 2 * l + 1];                           \
        const float mk1 = (4 * l + 1 <= Sb) ? 1.f : 0.f;                         \
        const float mk3 = (4 * l + 3 <= Sb) ? 1.f : 0.f;                         \
        float2 o;                                                                \
        o.x = med3c(__expf(base[c0]) * inv_s) * mk1;                             \
        o.y = med3c(__expf(base[c1]) * inv_s) * mk3;                             \
        *(float2*)(erow + 2 * l) = o;                                            \
    } else if (l == 50) {                                                        \
        float2 o;                                                                \
        o.x = med3c(__expf(base[0]) * inv_s);                                    \
        o.y = 0.f;                                                               \
        *(float2*)(erow + 100) = o;                                              \
    } }

    f32x4 a0, a1, a2, a3;                      // current row regs (set A)
    f32x4 b0, b1, b2, b3;                      // next row regs (set B)

    int row = gw;
    P1_ISSUE(a0, a1, a2, a3, row);
    for (;;) {
        // iteration A: compute set A, prefetch into set B
        int nxt = row + P1_STRIDE;
        if (nxt < NROWS) {
            P1_ISSUE(b0, b1, b2, b3, nxt);
            P1_WAIT4(a0, a1, a2, a3);
            P1_BODY(a0, a1, a2, a3, row);
        } else {
            P1_WAIT0(a0, a1, a2, a3);
            P1_BODY(a0, a1, a2, a3, row);
            break;
        }
        row = nxt;
        // iteration B: compute set B, prefetch into set A
        nxt = row + P1_STRIDE;
        if (nxt < NROWS) {
            P1_ISSUE(a0, a1, a2, a3, nxt);
            P1_WAIT4(b0, b1, b2, b3);
            P1_BODY(b0, b1, b2, b3, row);
        } else {
            P1_WAIT0(b0, b1, b2, b3);
            P1_BODY(b0, b1, b2, b3, row);
            break;
        }
        row = nxt;
    }
#undef P1_BODY
#undef P1_WAIT0
#undef P1_WAIT4
#undef P1_ISSUE
}

// ---------------------------------------------------------------------------
// Phase 2: byte-identical to R20 (70.0 us best): 1 wave/CU, PIPE=16,
// readlane blank, packed parity state, cadence-8 exact-pow2 rescale.
// ---------------------------------------------------------------------------
__global__ __launch_bounds__(64, 1) void k_alpha(
    const float* __restrict__ etab, const int* __restrict__ targets,
    const int* __restrict__ ilen, const int* __restrict__ tlen,
    float* __restrict__ out)
{
    const int b = blockIdx.x;
    const int l = threadIdx.x;                 // 0..63
    const float* eb = etab + (size_t)b * TDIM * EROW;
    const int eoff = (2 * l <= 100) ? 2 * l : 100;   // lanes>=50 -> blank pair
    const float* plane = eb + eoff;            // per-lane pair base

    f32x2 g = {0.f, 0.f};                      // skip gates (a1f, a3f)
    if (l < 50) {
        const int c0 = targets[b * UDIM + 2 * l];
        const int c1 = targets[b * UDIM + 2 * l + 1];
        g.y = (c1 != c0) ? 1.f : 0.f;
        if (l >= 1) g.x = (c0 != targets[b * UDIM + 2 * l - 1]) ? 1.f : 0.f;
    }

    const int u_b = tlen[b];
    const int Sb  = 2 * u_b;

    f32x2 pr0 = *(const f32x2*)plane;          // pre-sanitized in phase 1
    const float bl0 = __builtin_bit_cast(float,
        __builtin_amdgcn_readlane(__builtin_bit_cast(int, pr0.x), 50));
    const float F = 1e-30f * 0x1p110f;
    f32x2 E, O;
    E.x = (4 * l     <= Sb) ? F : 0.f;
    E.y = (4 * l + 2 <= Sb) ? F : 0.f;
    O.x = (4 * l + 1 <= Sb) ? F : 0.f;
    O.y = (4 * l + 3 <= Sb) ? F : 0.f;
    if (l == 0) {
        E.x = bl0   * 0x1p110f;                // s=0: blank
        O.x = pr0.x * 0x1p110f;                // s=1: first label
    }
    int ksum = -SCALE_EXP;                     // true log2 = log2(stored) + ksum

    int L = ilen[b];
    if (L > TDIM) L = TDIM;

    const unsigned long long ebu = (unsigned long long)eb;
    i32x4 srd;
    srd.x = (int)(ebu & 0xffffffffu);
    srd.y = (int)((ebu >> 32) & 0xffffu);
    srd.z = TDIM * EROW * 4;
    srd.w = 0x00020000;
    const int voff = eoff * 4;                 // per-lane pair byte offset
    int so = EROW * 4;                         // pair soffset (group base)

#define STEP(LAB_) {                                                             \
    const float ebv = __builtin_bit_cast(float,                                  \
        __builtin_amdgcn_readlane(__builtin_bit_cast(int, (LAB_).x), 50));       \
    f32x2 ebp; ebp.x = ebv; ebp.y = ebv;                                         \
    const float pP3 = dpp_shr1_zero(O.y);                                        \
    f32x2 sk; sk.x = pP3; sk.y = O.x;                                            \
    const f32x2 T  = E + O;                                                      \
    const f32x2 ev = (E + sk) * ebp;                                             \
    const f32x2 od = (sk * g + T) * (LAB_);                                      \
    E = ev; O = od; }

#define RESCALE() {                                                              \
    float pm = fmaxf(__builtin_amdgcn_fmed3f(                                    \
        fmaxf(E.x, O.x), fmaxf(E.y, O.y), INFINITY), 0x1p-10f);                  \
    pm = dppmax<0xB1>(pm);   /* quad_perm xor1  */                               \
    pm = dppmax<0x4E>(pm);   /* quad_perm xor2  */                               \
    pm = dppmax<0x141>(pm);  /* row_half_mirror */                               \
    pm = dppmax<0x140>(pm);  /* row_mirror      */                               \
    pm = dppmax<0x142>(pm);  /* row_bcast15    */                                \
    pm = dppmax<0x143>(pm);  /* row_bcast31    */                                \
    const int mb = __builtin_amdgcn_readlane(__builtin_bit_cast(int, pm), 63);   \
    const int ex = (mb >> 23) & 0xff;                                            \
    ksum += ex - (127 + SCALE_EXP);                                              \
    const float sc = __builtin_bit_cast(float, ((254 + SCALE_EXP) - ex) << 23);  \
    f32x2 scv; scv.x = sc; scv.y = sc;                                           \
    E = E * scv; O = O * scv; }

#define ISS(J, OFFP)                                                             \
    asm volatile("buffer_load_dwordx2 %0, %1, %2, %3 offen offset:" OFFP         \
        : "=v"(lab[J]) : "v"(voff), "s"(srd), "s"(so));

#define ISS8(G) \
    ISS((G)+0, "0");    ISS((G)+1, "416");                                       \
    ISS((G)+2, "832");  ISS((G)+3, "1248");                                      \
    ISS((G)+4, "1664"); ISS((G)+5, "2080");                                      \
    ISS((G)+6, "2496"); ISS((G)+7, "2912");

#define WAITG8(J) asm volatile("s_waitcnt vmcnt(8)"                              \
    : "+v"(lab[(J)]),   "+v"(lab[(J)+1]), "+v"(lab[(J)+2]), "+v"(lab[(J)+3]),    \
      "+v"(lab[(J)+4]), "+v"(lab[(J)+5]), "+v"(lab[(J)+6]), "+v"(lab[(J)+7]));

#define GROUP8(G) {                                                              \
    WAITG8(G);                                                                   \
    STEP(lab[(G)+0]); STEP(lab[(G)+1]);                                          \
    STEP(lab[(G)+2]); STEP(lab[(G)+3]);                                          \
    STEP(lab[(G)+4]); STEP(lab[(G)+5]);                                          \
    STEP(lab[(G)+6]); STEP(lab[(G)+7]);                                          \
    ISS8(G);                                                                     \
    so += 3328;                                                                  \
    RESCALE(); }

    f32x2 lab[PIPE];
    ISS8(0);  so += 3328;
    ISS8(8);  so += 3328;

    int t = 1;
    for (; t + PIPE - 1 < L; t += PIPE) {
        GROUP8(0);
        GROUP8(8);
    }
    asm volatile("s_waitcnt vmcnt(0)" ::: "memory");   // drain before tail

    for (; t < L; ++t) {
        f32x2 lb = *(const f32x2*)(plane + (size_t)t * EROW);
        STEP(lb);
        RESCALE();
    }
#undef GROUP8
#undef WAITG8
#undef ISS8
#undef ISS
#undef RESCALE
#undef STEP

    __shared__ float A[256];
    A[4 * l + 0] = __builtin_amdgcn_logf(fmaxf(E.x, 1e-38f));
    A[4 * l + 1] = __builtin_amdgcn_logf(fmaxf(O.x, 1e-38f));
    A[4 * l + 2] = __builtin_amdgcn_logf(fmaxf(E.y, 1e-38f));
    A[4 * l + 3] = __builtin_amdgcn_logf(fmaxf(O.y, 1e-38f));
    __syncthreads();
    if (l == 0) {
        const float x1 = A[2 * u_b - 1], x2 = A[2 * u_b];
        const float mx = fmaxf(x1, x2), mn = fminf(x1, x2);
        const float lse2 = mx + __builtin_amdgcn_logf(
            1.f + __builtin_amdgcn_exp2f(mn - mx));
        out[b] = -(LN2 * (lse2 + (float)ksum));
    }
}

extern "C" void kernel_launch(void* const* d_in, const int* in_sizes, int n_in,
                              void* d_out, int out_size, void* d_ws, size_t ws_size,
                              hipStream_t stream) {
    const float* lp      = (const float*)d_in[0];   // [T,B,V] f32
    const int*   targets = (const int*)d_in[1];     // [B,U] i32
    const int*   ilen    = (const int*)d_in[2];     // [B] i32
    const int*   tlen    = (const int*)d_in[3];     // [B] i32
    float* out  = (float*)d_out;                    // [B] f32
    float* etab = (float*)d_ws;                     // B*T*EROW*4 = 13.31 MB

    k_lsm_gather<<<P1_BLOCKS, 256, 0, stream>>>(lp, targets, tlen, etab);
    k_alpha<<<BDIM, 64, 0, stream>>>(etab, targets, ilen, tlen, out);
}